// Round 16
// baseline (24.956 us; speedup 1.0000x reference)
//
#include <hip/hip_runtime.h>
#include <math.h>

#define SEARCH 7
#define PAD 3
#define S2 49
#define KNN 7
#define NCLASSES 20
#define H 64
#define W 2048
#define NPTS 131072
#define NTILES 32
#define TROWS 70                 /* rows -3..66 (zero-padded) */
#define TCOLS 70                 /* cols -3..66 (circular)    */
#define SPT 32                   /* sub-blocks per tile */
#define SLICE (NPTS / SPT)       /* 4096 points scanned per block */
#define KBLOCK 256
#define QCAP 512

// f64-packed key: bits = (1<<62) | (distbits<<6) | j ; positive normal doubles,
// value order == bit order == exact lex-(dist, j) order (R9-proven).
#define SENTINEL_BITS 0x7FE0000000000000ull
#define CUTOFF_KEYMAX 0x4000000FE000003Full   /* (1<<62)|(0x3f800000<<6)|63 */

struct InvG { float v[S2]; };

// min/max bubble insert into sorted doubles s0..s6 (13 f64 ops, keys unique)
#define INSF(KEY) do {                                                  \
    double _x = (KEY);                                                  \
    double _t;                                                          \
    _t = fmin(s0, _x); _x = fmax(s0, _x); s0 = _t;                      \
    _t = fmin(s1, _x); _x = fmax(s1, _x); s1 = _t;                      \
    _t = fmin(s2, _x); _x = fmax(s2, _x); s2 = _t;                      \
    _t = fmin(s3, _x); _x = fmax(s3, _x); s3 = _t;                      \
    _t = fmin(s4, _x); _x = fmax(s4, _x); s4 = _t;                      \
    _t = fmin(s5, _x); _x = fmax(s5, _x); s5 = _t;                      \
    s6 = fmin(s6, _x);                                                  \
} while (0)

__global__ __launch_bounds__(KBLOCK, 4) void knn_kernel(
    const float* __restrict__ proj_range,
    const float* __restrict__ unproj_range,
    const int* __restrict__ proj_argmax,
    const int* __restrict__ pxv,
    const int* __restrict__ pyv,
    int* __restrict__ outv,
    InvG invg)
{
    __shared__ float  ftile[TROWS * TCOLS];
    __shared__ unsigned queue[QCAP];
    __shared__ int qcnt;

    const int tid  = threadIdx.x;
    const int t    = blockIdx.x >> 5;        // tile
    const int sub  = blockIdx.x & 31;        // slice
    const int tbase = t << 6;
    const int lane = tid & 63;
    const int wave = tid >> 6;               // 0..3

    if (tid == 0) qcnt = 0;

    // stage 70x70 padded range tile (classes gathered from L2 in epilogue)
#pragma unroll
    for (int it = 0; it < 18; ++it) {
        int r = it * 4 + wave;
        if (r < TROWS) {
            int sr = r - 3;
            bool vr = (unsigned)sr < (unsigned)H;
            int gb = (vr ? sr : 0) * W;
            int ca = (tbase - 3 + lane) & (W - 1);
            float fv = proj_range[gb + ca];
            ftile[r * TCOLS + lane] = vr ? fv : 0.0f;
            if (lane < TCOLS - 64) {
                int cb = (tbase - 3 + 64 + lane) & (W - 1);
                float fv2 = proj_range[gb + cb];
                ftile[r * TCOLS + 64 + lane] = vr ? fv2 : 0.0f;
            }
        }
    }
    __syncthreads();                          // tile ready, qcnt=0 visible

    // scan own slice of px; enqueue matches (px>>6 == t)  (R8/R9-proven)
    {
        const int4* px4 = (const int4*)pxv;
        int base4 = (sub * SLICE) >> 2;
#pragma unroll
        for (int k = 0; k < 4; ++k) {
            int idx4 = base4 + k * KBLOCK + tid;
            int4 v = px4[idx4];
            int i0x = idx4 * 4;
#pragma unroll
            for (int e = 0; e < 4; ++e) {
                int x = (e == 0) ? v.x : (e == 1) ? v.y : (e == 2) ? v.z : v.w;
                if ((x >> 6) == t) {
                    int i = i0x + e;
                    int y = pyv[i];
                    int pos = atomicAdd(&qcnt, 1);
                    if (pos < QCAP)
                        queue[pos] = (unsigned)i | ((unsigned)(x & 63) << 17)
                                                | ((unsigned)y << 23);
                }
            }
        }
    }
    __syncthreads();                          // queue ready; LAST barrier
    const int count = min(qcnt, QCAP);

    // two lanes per point (even: j 0..23, odd: j 24..48), SAME instruction
    // stream with lane-selected constants -> no divergent role paths.
    const bool isB = (tid & 1) != 0;
    const int jadd = isB ? 25 : 0;

    for (int base = 0; base < count; base += KBLOCK / 2) {
        int pt = base + (tid >> 1);
        if (pt < count) {                     // pair-uniform predicate
            unsigned pk = queue[pt];
            int i  = (int)(pk & 0x1FFFFu);
            int xl = (int)((pk >> 17) & 63u);
            int y  = (int)((pk >> 23) & 63u);
            float u = unproj_range[i];
            int abase = y * TCOLS + xl;       // addr = abase + (j/7)*TCOLS + j%7

            const double sent = __longlong_as_double((long long)SENTINEL_BITS);
            double s0 = sent, s1 = sent, s2 = sent, s3 = sent,
                   s4 = sent, s5 = sent, s6 = sent;

            // center (j=24): real key on odd lanes, sentinel no-op on even
            {
                unsigned long long ck = isB ? ((1ull << 62) | 24ull) : SENTINEL_BITS;
                INSF(__longlong_as_double((long long)ck));
            }

#pragma unroll
            for (int s = 0; s < 24; ++s) {
                const int jA = s, jB = s + 25;
                const int offA = (jA / 7) * TCOLS + (jA % 7);
                const int offB = (jB / 7) * TCOLS + (jB % 7);
                int off = isB ? offB : offA;              // 1-2 VALU
                float ig = isB ? invg.v[jB] : invg.v[jA]; // sgpr consts + cndmask
                float nb = ftile[abase + off];
                nb = (nb < 0.0f) ? __builtin_inff() : nb;
                float d = fabsf(nb - u) * ig;
                unsigned long long kb = (1ull << 62)
                    | ((unsigned long long)__float_as_uint(d) << 6)
                    | (unsigned)(s + jadd);
                INSF(__longlong_as_double((long long)kb));
            }

            // partner exchange (lane^1, same wave, no barrier):
            double p0 = __shfl_xor(s0, 1, 64);
            double p1 = __shfl_xor(s1, 1, 64);
            double p2 = __shfl_xor(s2, 1, 64);
            double p3 = __shfl_xor(s3, 1, 64);
            double p4 = __shfl_xor(s4, 1, 64);
            double p5 = __shfl_xor(s5, 1, 64);
            double p6 = __shfl_xor(s6, 1, 64);
            // Batcher half-cleaner: mins of (a_k, b_{6-k}) = 7 smallest of 14
            double m0 = fmin(s0, p6);
            double m1 = fmin(s1, p5);
            double m2 = fmin(s2, p4);
            double m3 = fmin(s3, p3);
            double m4 = fmin(s4, p2);
            double m5 = fmin(s5, p1);
            double m6 = fmin(s6, p0);

            const double cutmax = __longlong_as_double((long long)CUTOFF_KEYMAX);
            int c0, c1, c2, c3, c4, c5, c6;
            // winner classes from global proj_argmax (L2-hot; R13-proven)
#define CLSK(MK, CK) do {                                                \
            long long kb = __double_as_longlong(MK);                     \
            int j = (int)(kb & 63);                                      \
            bool sel = (MK) <= cutmax;                                   \
            int dy7 = (j * 37) >> 8;                                     \
            int sr = y + dy7 - 3;                                        \
            bool vrow = (unsigned)sr < (unsigned)H;                      \
            int src = min(max(sr, 0), H - 1);                            \
            int colw = (tbase - 3 + xl + (j - dy7 * 7)) & (W - 1);       \
            int cc = proj_argmax[src * W + colw];                        \
            CK = (sel && vrow) ? cc : 0;                                 \
        } while (0)
            CLSK(m0, c0); CLSK(m1, c1); CLSK(m2, c2); CLSK(m3, c3);
            CLSK(m4, c4); CLSK(m5, c5); CLSK(m6, c6);
#undef CLSK

            int n0 = 1, n1 = 1, n2 = 1, n3 = 1, n4 = 1, n5 = 1, n6 = 1;
#define PAIRV(A, B) do { bool e = (c##A == c##B); n##A += e ? 1 : 0; n##B += e ? 1 : 0; } while (0)
            PAIRV(0,1); PAIRV(0,2); PAIRV(0,3); PAIRV(0,4); PAIRV(0,5); PAIRV(0,6);
            PAIRV(1,2); PAIRV(1,3); PAIRV(1,4); PAIRV(1,5); PAIRV(1,6);
            PAIRV(2,3); PAIRV(2,4); PAIRV(2,5); PAIRV(2,6);
            PAIRV(3,4); PAIRV(3,5); PAIRV(3,6);
            PAIRV(4,5); PAIRV(4,6);
            PAIRV(5,6);
#undef PAIRV

            int best = 0;
#define SCORE(K) do {                                                    \
            bool valid = (unsigned)(c##K - 1) < (unsigned)(NCLASSES - 1);\
            int sc = valid ? ((n##K << 5) | (31 - c##K)) : 0;            \
            best = max(best, sc);                                        \
        } while (0)
            SCORE(0); SCORE(1); SCORE(2); SCORE(3); SCORE(4); SCORE(5); SCORE(6);
#undef SCORE
            if (!isB) {
                int res = (best == 0) ? 1 : (31 - (best & 31));
                __builtin_nontemporal_store(res, &outv[i]);
            }
        }
    }
}

extern "C" void kernel_launch(void* const* d_in, const int* in_sizes, int n_in,
                              void* d_out, int out_size, void* d_ws, size_t ws_size,
                              hipStream_t stream) {
    const float* proj_range   = (const float*)d_in[0];
    const float* unproj_range = (const float*)d_in[1];
    const int*   proj_argmax  = (const int*)d_in[2];
    const int*   px           = (const int*)d_in[3];
    const int*   py           = (const int*)d_in[4];
    int* out = (int*)d_out;

    // Emulate numpy float32 pipeline for the inverse-gaussian table.
    InvG invg;
    float g[S2];
    for (int yy = 0; yy < SEARCH; ++yy) {
        for (int xx = 0; xx < SEARCH; ++xx) {
            float fdx = (float)xx - 3.0f;
            float fdy = (float)yy - 3.0f;
            float s   = fdx * fdx + fdy * fdy;
            float arg = -s / 2.0f;
            float e   = (float)exp((double)arg);
            float gg  = e / 6.2831855f;
            g[yy * SEARCH + xx] = gg;
        }
    }
    float r[8];
    for (int tt = 0; tt < 8; ++tt) r[tt] = g[tt];
    int ii;
    for (ii = 8; ii + 8 <= 48; ii += 8)
        for (int tt = 0; tt < 8; ++tt) r[tt] += g[ii + tt];
    float ssum = ((r[0] + r[1]) + (r[2] + r[3])) + ((r[4] + r[5]) + (r[6] + r[7]));
    for (; ii < S2; ++ii) ssum += g[ii];
    for (int tt = 0; tt < S2; ++tt) invg.v[tt] = 1.0f - (g[tt] / ssum);

    knn_kernel<<<NTILES * SPT, KBLOCK, 0, stream>>>(
        proj_range, unproj_range, proj_argmax, px, py, out, invg);
}

// Round 17
// 21.663 us; speedup vs baseline: 1.1520x; 1.1520x over previous
//
#include <hip/hip_runtime.h>
#include <math.h>

#define SEARCH 7
#define PAD 3
#define S2 49
#define KNN 7
#define NCLASSES 20
#define H 64
#define W 2048
#define NPTS 131072
#define NTILES 32
#define TROWS 70                 /* rows -3..66 (zero-padded) */
#define TCOLS 70                 /* cols -3..66 (circular)    */
#define SPT 16                   /* sub-blocks per tile: count ~= KBLOCK */
#define SLICE (NPTS / SPT)       /* 8192 points scanned per block */
#define KBLOCK 256
#define QCAP 512

// f64-packed key: bits = (1<<62) | (distbits<<6) | j ; positive normal doubles,
// value order == bit order == exact lex-(dist, j) order (R9-proven).
#define SENTINEL_BITS 0x7FE0000000000000ull
#define CUTOFF_KEYMAX 0x4000000FE000003Full   /* (1<<62)|(0x3f800000<<6)|63 */

struct InvG { float v[S2]; };

// min/max bubble insert into sorted doubles s0..s6 (13 f64 ops, keys unique)
#define INSF(KEY) do {                                                  \
    double _x = (KEY);                                                  \
    double _t;                                                          \
    _t = fmin(s0, _x); _x = fmax(s0, _x); s0 = _t;                      \
    _t = fmin(s1, _x); _x = fmax(s1, _x); s1 = _t;                      \
    _t = fmin(s2, _x); _x = fmax(s2, _x); s2 = _t;                      \
    _t = fmin(s3, _x); _x = fmax(s3, _x); s3 = _t;                      \
    _t = fmin(s4, _x); _x = fmax(s4, _x); s4 = _t;                      \
    _t = fmin(s5, _x); _x = fmax(s5, _x); s5 = _t;                      \
    s6 = fmin(s6, _x);                                                  \
} while (0)

#define CAND(J, RB, DX) do {                                            \
    float nb = ftile[(RB) + (DX)];                                      \
    nb = (nb < 0.0f) ? __builtin_inff() : nb;                           \
    float d = fabsf(nb - u) * invg.v[J];                                \
    unsigned long long kb = (1ull << 62)                                \
        | ((unsigned long long)__float_as_uint(d) << 6)                 \
        | (unsigned)(J);                                                \
    INSF(__longlong_as_double((long long)kb));                          \
} while (0)

__global__ __launch_bounds__(KBLOCK, 4) void knn_kernel(
    const float* __restrict__ proj_range,
    const float* __restrict__ unproj_range,
    const int* __restrict__ proj_argmax,
    const int* __restrict__ pxv,
    const int* __restrict__ pyv,
    int* __restrict__ outv,
    InvG invg)
{
    __shared__ float  ftile[TROWS * TCOLS];
    __shared__ unsigned queue[QCAP];
    __shared__ int qcnt;

    const int tid  = threadIdx.x;
    const int t    = blockIdx.x >> 4;        // tile (16 sub-blocks per tile)
    const int sub  = blockIdx.x & 15;        // slice
    const int tbase = t << 6;
    const int lane = tid & 63;
    const int wave = tid >> 6;               // 0..3

    if (tid == 0) qcnt = 0;

    // stage 70x70 padded range tile (classes gathered from L2 in epilogue)
#pragma unroll
    for (int it = 0; it < 18; ++it) {
        int r = it * 4 + wave;
        if (r < TROWS) {
            int sr = r - 3;
            bool vr = (unsigned)sr < (unsigned)H;
            int gb = (vr ? sr : 0) * W;
            int ca = (tbase - 3 + lane) & (W - 1);
            float fv = proj_range[gb + ca];
            ftile[r * TCOLS + lane] = vr ? fv : 0.0f;
            if (lane < TCOLS - 64) {
                int cb = (tbase - 3 + 64 + lane) & (W - 1);
                float fv2 = proj_range[gb + cb];
                ftile[r * TCOLS + 64 + lane] = vr ? fv2 : 0.0f;
            }
        }
    }
    __syncthreads();                          // tile ready, qcnt=0 visible

    // scan own slice of px; enqueue matches (px>>6 == t)  (R8/R9-proven)
    {
        const int4* px4 = (const int4*)pxv;
        int base4 = (sub * SLICE) >> 2;
#pragma unroll
        for (int k = 0; k < 8; ++k) {
            int idx4 = base4 + k * KBLOCK + tid;
            int4 v = px4[idx4];
            int i0x = idx4 * 4;
#pragma unroll
            for (int e = 0; e < 4; ++e) {
                int x = (e == 0) ? v.x : (e == 1) ? v.y : (e == 2) ? v.z : v.w;
                if ((x >> 6) == t) {
                    int i = i0x + e;
                    int y = pyv[i];
                    int pos = atomicAdd(&qcnt, 1);
                    if (pos < QCAP)
                        queue[pos] = (unsigned)i | ((unsigned)(x & 63) << 17)
                                                | ((unsigned)y << 23);
                }
            }
        }
    }
    __syncthreads();                          // queue ready; LAST barrier
    const int count = min(qcnt, QCAP);

    // one thread = one point, full 49-candidate chain, no further barriers
    for (int slot = tid; slot < count; slot += KBLOCK) {
        unsigned pk = queue[slot];
        int i  = (int)(pk & 0x1FFFFu);
        int xl = (int)((pk >> 17) & 63u);
        int y  = (int)((pk >> 23) & 63u);
        float u = unproj_range[i];

        const double sent = __longlong_as_double((long long)SENTINEL_BITS);
        double s0 = sent, s1 = sent, s2 = sent, s3 = sent,
               s4 = sent, s5 = sent, s6 = sent;

        INSF(__longlong_as_double((long long)((1ull << 62) | 24ull)));  // center

#pragma unroll
        for (int dy = -3; dy <= 3; ++dy) {
            int rb = (y + dy + 3) * TCOLS + xl + 3;
#pragma unroll
            for (int dx = -3; dx <= 3; ++dx) {
                const int j = (dy + 3) * 7 + (dx + 3);
                if (j == 24) continue;        // center handled above
                CAND(j, rb, dx);
            }
        }

        const double cutmax = __longlong_as_double((long long)CUTOFF_KEYMAX);
        int c0, c1, c2, c3, c4, c5, c6;
        // winner classes gathered from global proj_argmax (L2-hot);
        // zero-pad rows -> class 0; circular in W (R13-proven pattern)
#define CLSK(MK, CK) do {                                                \
        long long kb = __double_as_longlong(MK);                         \
        int j = (int)(kb & 63);                                          \
        bool sel = (MK) <= cutmax;                                       \
        int dy7 = (j * 37) >> 8;                                         \
        int sr = y + dy7 - 3;                                            \
        bool vrow = (unsigned)sr < (unsigned)H;                          \
        int src = min(max(sr, 0), H - 1);                                \
        int colw = (tbase - 3 + xl + (j - dy7 * 7)) & (W - 1);           \
        int cc = proj_argmax[src * W + colw];                            \
        CK = (sel && vrow) ? cc : 0;                                     \
    } while (0)
        CLSK(s0, c0); CLSK(s1, c1); CLSK(s2, c2); CLSK(s3, c3);
        CLSK(s4, c4); CLSK(s5, c5); CLSK(s6, c6);
#undef CLSK

        int n0 = 1, n1 = 1, n2 = 1, n3 = 1, n4 = 1, n5 = 1, n6 = 1;
#define PAIRV(A, B) do { bool e = (c##A == c##B); n##A += e ? 1 : 0; n##B += e ? 1 : 0; } while (0)
        PAIRV(0,1); PAIRV(0,2); PAIRV(0,3); PAIRV(0,4); PAIRV(0,5); PAIRV(0,6);
        PAIRV(1,2); PAIRV(1,3); PAIRV(1,4); PAIRV(1,5); PAIRV(1,6);
        PAIRV(2,3); PAIRV(2,4); PAIRV(2,5); PAIRV(2,6);
        PAIRV(3,4); PAIRV(3,5); PAIRV(3,6);
        PAIRV(4,5); PAIRV(4,6);
        PAIRV(5,6);
#undef PAIRV

        int best = 0;
#define SCORE(K) do {                                                    \
        bool valid = (unsigned)(c##K - 1) < (unsigned)(NCLASSES - 1);    \
        int sc = valid ? ((n##K << 5) | (31 - c##K)) : 0;                \
        best = max(best, sc);                                            \
    } while (0)
        SCORE(0); SCORE(1); SCORE(2); SCORE(3); SCORE(4); SCORE(5); SCORE(6);
#undef SCORE
        int res = (best == 0) ? 1 : (31 - (best & 31));
        __builtin_nontemporal_store(res, &outv[i]);
    }
}

extern "C" void kernel_launch(void* const* d_in, const int* in_sizes, int n_in,
                              void* d_out, int out_size, void* d_ws, size_t ws_size,
                              hipStream_t stream) {
    const float* proj_range   = (const float*)d_in[0];
    const float* unproj_range = (const float*)d_in[1];
    const int*   proj_argmax  = (const int*)d_in[2];
    const int*   px           = (const int*)d_in[3];
    const int*   py           = (const int*)d_in[4];
    int* out = (int*)d_out;

    // Emulate numpy float32 pipeline for the inverse-gaussian table.
    InvG invg;
    float g[S2];
    for (int yy = 0; yy < SEARCH; ++yy) {
        for (int xx = 0; xx < SEARCH; ++xx) {
            float fdx = (float)xx - 3.0f;
            float fdy = (float)yy - 3.0f;
            float s   = fdx * fdx + fdy * fdy;
            float arg = -s / 2.0f;
            float e   = (float)exp((double)arg);
            float gg  = e / 6.2831855f;
            g[yy * SEARCH + xx] = gg;
        }
    }
    float r[8];
    for (int tt = 0; tt < 8; ++tt) r[tt] = g[tt];
    int ii;
    for (ii = 8; ii + 8 <= 48; ii += 8)
        for (int tt = 0; tt < 8; ++tt) r[tt] += g[ii + tt];
    float ssum = ((r[0] + r[1]) + (r[2] + r[3])) + ((r[4] + r[5]) + (r[6] + r[7]));
    for (; ii < S2; ++ii) ssum += g[ii];
    for (int tt = 0; tt < S2; ++tt) invg.v[tt] = 1.0f - (g[tt] / ssum);

    knn_kernel<<<NTILES * SPT, KBLOCK, 0, stream>>>(
        proj_range, unproj_range, proj_argmax, px, py, out, invg);
}

// Round 18
// 19.602 us; speedup vs baseline: 1.2731x; 1.1052x over previous
//
#include <hip/hip_runtime.h>
#include <math.h>

#define SEARCH 7
#define PAD 3
#define S2 49
#define KNN 7
#define NCLASSES 20
#define H 64
#define W 2048
#define NPTS 131072
#define NTILES 32
#define TROWS 70                 /* rows -3..66 (zero-padded) */
#define TCOLS 70                 /* cols -3..66 (circular)    */
#define SPT 32                   /* sub-blocks per tile */
#define SLICE (NPTS / SPT)       /* 4096 points scanned per block */
#define KBLOCK 256
#define QCAP 512

// f64-packed key: bits = (1<<62) | (distbits<<6) | j ; positive normal doubles,
// value order == bit order == exact lex-(dist, j) order (R9-proven).
#define SENTINEL_BITS 0x7FE0000000000000ull
#define CUTOFF_KEYMAX 0x4000000FE000003Full   /* (1<<62)|(0x3f800000<<6)|63 */

struct InvG { float v[S2]; };

// min/max bubble insert into sorted doubles <P>0..<P>6 (13 f64 ops, keys unique)
#define INSF_P(P, KEY) do {                                             \
    double _x = (KEY);                                                  \
    double _t;                                                          \
    _t = fmin(P##0, _x); _x = fmax(P##0, _x); P##0 = _t;                \
    _t = fmin(P##1, _x); _x = fmax(P##1, _x); P##1 = _t;                \
    _t = fmin(P##2, _x); _x = fmax(P##2, _x); P##2 = _t;                \
    _t = fmin(P##3, _x); _x = fmax(P##3, _x); P##3 = _t;                \
    _t = fmin(P##4, _x); _x = fmax(P##4, _x); P##4 = _t;                \
    _t = fmin(P##5, _x); _x = fmax(P##5, _x); P##5 = _t;                \
    P##6 = fmin(P##6, _x);                                              \
} while (0)

// candidate j -> key inserted into chain P (A or B)
#define CANDP(P, J, RB, DX) do {                                        \
    float nb = ftile[(RB) + (DX)];                                      \
    nb = (nb < 0.0f) ? __builtin_inff() : nb;                           \
    float d = fabsf(nb - u) * invg.v[J];                                \
    unsigned long long kb = (1ull << 62)                                \
        | ((unsigned long long)__float_as_uint(d) << 6)                 \
        | (unsigned)(J);                                                \
    INSF_P(P, __longlong_as_double((long long)kb));                     \
} while (0)

__global__ __launch_bounds__(KBLOCK, 4) void knn_kernel(
    const float* __restrict__ proj_range,
    const float* __restrict__ unproj_range,
    const int* __restrict__ proj_argmax,
    const int* __restrict__ pxv,
    const int* __restrict__ pyv,
    int* __restrict__ outv,
    InvG invg)
{
    __shared__ float  ftile[TROWS * TCOLS];
    __shared__ unsigned queue[QCAP];
    __shared__ int qcnt;

    const int tid  = threadIdx.x;
    const int t    = blockIdx.x >> 5;        // tile
    const int sub  = blockIdx.x & 31;        // slice
    const int tbase = t << 6;
    const int lane = tid & 63;
    const int wave = tid >> 6;               // 0..3

    if (tid == 0) qcnt = 0;

    // stage 70x70 padded range tile (classes gathered from L2 in epilogue)
#pragma unroll
    for (int it = 0; it < 18; ++it) {
        int r = it * 4 + wave;
        if (r < TROWS) {
            int sr = r - 3;
            bool vr = (unsigned)sr < (unsigned)H;
            int gb = (vr ? sr : 0) * W;
            int ca = (tbase - 3 + lane) & (W - 1);
            float fv = proj_range[gb + ca];
            ftile[r * TCOLS + lane] = vr ? fv : 0.0f;
            if (lane < TCOLS - 64) {
                int cb = (tbase - 3 + 64 + lane) & (W - 1);
                float fv2 = proj_range[gb + cb];
                ftile[r * TCOLS + 64 + lane] = vr ? fv2 : 0.0f;
            }
        }
    }
    __syncthreads();                          // tile ready, qcnt=0 visible

    // scan own slice of px; enqueue matches (px>>6 == t)  (R8/R9-proven)
    {
        const int4* px4 = (const int4*)pxv;
        int base4 = (sub * SLICE) >> 2;
#pragma unroll
        for (int k = 0; k < 4; ++k) {
            int idx4 = base4 + k * KBLOCK + tid;
            int4 v = px4[idx4];
            int i0x = idx4 * 4;
#pragma unroll
            for (int e = 0; e < 4; ++e) {
                int x = (e == 0) ? v.x : (e == 1) ? v.y : (e == 2) ? v.z : v.w;
                if ((x >> 6) == t) {
                    int i = i0x + e;
                    int y = pyv[i];
                    int pos = atomicAdd(&qcnt, 1);
                    if (pos < QCAP)
                        queue[pos] = (unsigned)i | ((unsigned)(x & 63) << 17)
                                                | ((unsigned)y << 23);
                }
            }
        }
    }
    __syncthreads();                          // queue ready; LAST barrier
    const int count = min(qcnt, QCAP);

    // one thread = one point; TWO independent insert chains (A/B) halve the
    // serial dependency depth; final half-cleaner gives the 7-smallest set.
    for (int slot = tid; slot < count; slot += KBLOCK) {
        unsigned pk = queue[slot];
        int i  = (int)(pk & 0x1FFFFu);
        int xl = (int)((pk >> 17) & 63u);
        int y  = (int)((pk >> 23) & 63u);
        float u = unproj_range[i];

        const double sent = __longlong_as_double((long long)SENTINEL_BITS);
        double a0 = sent, a1 = sent, a2 = sent, a3 = sent,
               a4 = sent, a5 = sent, a6 = sent;
        double b0 = sent, b1 = sent, b2 = sent, b3 = sent,
               b4 = sent, b5 = sent, b6 = sent;

        INSF_P(a, __longlong_as_double((long long)((1ull << 62) | 24ull))); // center

#pragma unroll
        for (int dy = -3; dy <= 3; ++dy) {
            int rb = (y + dy + 3) * TCOLS + xl + 3;
#pragma unroll
            for (int dx = -3; dx <= 3; ++dx) {
                const int j = (dy + 3) * 7 + (dx + 3);
                if (j == 24) continue;        // center handled above
                if (j & 1) { CANDP(a, j, rb, dx); }
                else       { CANDP(b, j, rb, dx); }
            }
        }

        // register half-cleaner: the 7 smallest of the 14 (set, order-free)
        double m0 = fmin(a0, b6);
        double m1 = fmin(a1, b5);
        double m2 = fmin(a2, b4);
        double m3 = fmin(a3, b3);
        double m4 = fmin(a4, b2);
        double m5 = fmin(a5, b1);
        double m6 = fmin(a6, b0);

        const double cutmax = __longlong_as_double((long long)CUTOFF_KEYMAX);
        int c0, c1, c2, c3, c4, c5, c6;
        // winner classes gathered from global proj_argmax (L2-hot);
        // zero-pad rows -> class 0; circular in W (R13-proven pattern)
#define CLSK(MK, CK) do {                                                \
        long long kb = __double_as_longlong(MK);                         \
        int j = (int)(kb & 63);                                          \
        bool sel = (MK) <= cutmax;                                       \
        int dy7 = (j * 37) >> 8;                                         \
        int sr = y + dy7 - 3;                                            \
        bool vrow = (unsigned)sr < (unsigned)H;                          \
        int src = min(max(sr, 0), H - 1);                                \
        int colw = (tbase - 3 + xl + (j - dy7 * 7)) & (W - 1);           \
        int cc = proj_argmax[src * W + colw];                            \
        CK = (sel && vrow) ? cc : 0;                                     \
    } while (0)
        CLSK(m0, c0); CLSK(m1, c1); CLSK(m2, c2); CLSK(m3, c3);
        CLSK(m4, c4); CLSK(m5, c5); CLSK(m6, c6);
#undef CLSK

        int n0 = 1, n1 = 1, n2 = 1, n3 = 1, n4 = 1, n5 = 1, n6 = 1;
#define PAIRV(A, B) do { bool e = (c##A == c##B); n##A += e ? 1 : 0; n##B += e ? 1 : 0; } while (0)
        PAIRV(0,1); PAIRV(0,2); PAIRV(0,3); PAIRV(0,4); PAIRV(0,5); PAIRV(0,6);
        PAIRV(1,2); PAIRV(1,3); PAIRV(1,4); PAIRV(1,5); PAIRV(1,6);
        PAIRV(2,3); PAIRV(2,4); PAIRV(2,5); PAIRV(2,6);
        PAIRV(3,4); PAIRV(3,5); PAIRV(3,6);
        PAIRV(4,5); PAIRV(4,6);
        PAIRV(5,6);
#undef PAIRV

        int best = 0;
#define SCORE(K) do {                                                    \
        bool valid = (unsigned)(c##K - 1) < (unsigned)(NCLASSES - 1);    \
        int sc = valid ? ((n##K << 5) | (31 - c##K)) : 0;                \
        best = max(best, sc);                                            \
    } while (0)
        SCORE(0); SCORE(1); SCORE(2); SCORE(3); SCORE(4); SCORE(5); SCORE(6);
#undef SCORE
        int res = (best == 0) ? 1 : (31 - (best & 31));
        __builtin_nontemporal_store(res, &outv[i]);
    }
}

extern "C" void kernel_launch(void* const* d_in, const int* in_sizes, int n_in,
                              void* d_out, int out_size, void* d_ws, size_t ws_size,
                              hipStream_t stream) {
    const float* proj_range   = (const float*)d_in[0];
    const float* unproj_range = (const float*)d_in[1];
    const int*   proj_argmax  = (const int*)d_in[2];
    const int*   px           = (const int*)d_in[3];
    const int*   py           = (const int*)d_in[4];
    int* out = (int*)d_out;

    // Emulate numpy float32 pipeline for the inverse-gaussian table.
    InvG invg;
    float g[S2];
    for (int yy = 0; yy < SEARCH; ++yy) {
        for (int xx = 0; xx < SEARCH; ++xx) {
            float fdx = (float)xx - 3.0f;
            float fdy = (float)yy - 3.0f;
            float s   = fdx * fdx + fdy * fdy;
            float arg = -s / 2.0f;
            float e   = (float)exp((double)arg);
            float gg  = e / 6.2831855f;
            g[yy * SEARCH + xx] = gg;
        }
    }
    float r[8];
    for (int tt = 0; tt < 8; ++tt) r[tt] = g[tt];
    int ii;
    for (ii = 8; ii + 8 <= 48; ii += 8)
        for (int tt = 0; tt < 8; ++tt) r[tt] += g[ii + tt];
    float ssum = ((r[0] + r[1]) + (r[2] + r[3])) + ((r[4] + r[5]) + (r[6] + r[7]));
    for (; ii < S2; ++ii) ssum += g[ii];
    for (int tt = 0; tt < S2; ++tt) invg.v[tt] = 1.0f - (g[tt] / ssum);

    knn_kernel<<<NTILES * SPT, KBLOCK, 0, stream>>>(
        proj_range, unproj_range, proj_argmax, px, py, out, invg);
}

// Round 19
// 19.559 us; speedup vs baseline: 1.2759x; 1.0022x over previous
//
#include <hip/hip_runtime.h>
#include <math.h>

#define SEARCH 7
#define PAD 3
#define S2 49
#define KNN 7
#define NCLASSES 20
#define H 64
#define W 2048
#define NPTS 131072
#define NTILES 32
#define TROWS 70                 /* rows -3..66 (zero-padded) */
#define TCOLS 70                 /* cols -3..66 (circular)    */
#define SPT 32                   /* sub-blocks per tile */
#define SLICE (NPTS / SPT)       /* 4096 points scanned per block */
#define KBLOCK 256
#define SEGCAP 128               /* per-wave queue segment (mean 32 + 17 sigma) */

// f64-packed key: bits = (1<<62) | (distbits<<6) | j ; positive normal doubles,
// value order == bit order == exact lex-(dist, j) order (R9-proven).
#define SENTINEL_BITS 0x7FE0000000000000ull
#define CUTOFF_KEYMAX 0x4000000FE000003Full   /* (1<<62)|(0x3f800000<<6)|63 */

struct InvG { float v[S2]; };

// min/max bubble insert into sorted doubles <P>0..<P>6 (13 f64 ops, keys unique)
#define INSF_P(P, KEY) do {                                             \
    double _x = (KEY);                                                  \
    double _t;                                                          \
    _t = fmin(P##0, _x); _x = fmax(P##0, _x); P##0 = _t;                \
    _t = fmin(P##1, _x); _x = fmax(P##1, _x); P##1 = _t;                \
    _t = fmin(P##2, _x); _x = fmax(P##2, _x); P##2 = _t;                \
    _t = fmin(P##3, _x); _x = fmax(P##3, _x); P##3 = _t;                \
    _t = fmin(P##4, _x); _x = fmax(P##4, _x); P##4 = _t;                \
    _t = fmin(P##5, _x); _x = fmax(P##5, _x); P##5 = _t;                \
    P##6 = fmin(P##6, _x);                                              \
} while (0)

// candidate j -> key inserted into chain P (a or b)
#define CANDP(P, J, RB, DX) do {                                        \
    float nb = ftile[(RB) + (DX)];                                      \
    nb = (nb < 0.0f) ? __builtin_inff() : nb;                           \
    float d = fabsf(nb - u) * invg.v[J];                                \
    unsigned long long kb = (1ull << 62)                                \
        | ((unsigned long long)__float_as_uint(d) << 6)                 \
        | (unsigned)(J);                                                \
    INSF_P(P, __longlong_as_double((long long)kb));                     \
} while (0)

__global__ __launch_bounds__(KBLOCK, 4) void knn_kernel(
    const float* __restrict__ proj_range,
    const float* __restrict__ unproj_range,
    const int* __restrict__ proj_argmax,
    const int* __restrict__ pxv,
    const int* __restrict__ pyv,
    int* __restrict__ outv,
    InvG invg)
{
    __shared__ float  ftile[TROWS * TCOLS];
    __shared__ unsigned queue[4 * SEGCAP];
    __shared__ int wcounts[4];

    const int tid  = threadIdx.x;
    const int t    = blockIdx.x >> 5;        // tile
    const int sub  = blockIdx.x & 31;        // slice
    const int tbase = t << 6;
    const int lane = tid & 63;
    const int wave = tid >> 6;               // 0..3

    // ---- single barrier interval: staging loads + scan loads overlap in VMEM

    // stage 70x70 padded range tile (classes gathered from L2 in epilogue)
#pragma unroll
    for (int it = 0; it < 18; ++it) {
        int r = it * 4 + wave;
        if (r < TROWS) {
            int sr = r - 3;
            bool vr = (unsigned)sr < (unsigned)H;
            int gb = (vr ? sr : 0) * W;
            int ca = (tbase - 3 + lane) & (W - 1);
            float fv = proj_range[gb + ca];
            ftile[r * TCOLS + lane] = vr ? fv : 0.0f;
            if (lane < TCOLS - 64) {
                int cb = (tbase - 3 + 64 + lane) & (W - 1);
                float fv2 = proj_range[gb + cb];
                ftile[r * TCOLS + 64 + lane] = vr ? fv2 : 0.0f;
            }
        }
    }

    // scan own slice of px; per-wave ballot compaction into private segment
    // (no atomics, no cross-wave coordination until the one barrier)
    {
        const int4* px4 = (const int4*)pxv;
        int base4 = (sub * SLICE) >> 2;      // wave w handles iters k: lanes cover
        int wcnt = 0;                        // wave-uniform running count
#pragma unroll
        for (int k = 0; k < 4; ++k) {
            int idx4 = base4 + (k * 4 + wave) * 64 + lane;   // 64 int4 per wave-iter
            int4 v = px4[idx4];
            int i0x = idx4 * 4;
#pragma unroll
            for (int e = 0; e < 4; ++e) {
                int x = (e == 0) ? v.x : (e == 1) ? v.y : (e == 2) ? v.z : v.w;
                bool match = (x >> 6) == t;
                unsigned long long m = __ballot(match);
                int pre = __popcll(m & ((1ull << lane) - 1ull));
                if (match) {
                    int i = i0x + e;
                    int y = pyv[i];
                    int pos = wcnt + pre;
                    if (pos < SEGCAP)
                        queue[wave * SEGCAP + pos] =
                            (unsigned)i | ((unsigned)(x & 63) << 17)
                                        | ((unsigned)y << 23);
                }
                wcnt += __popcll(m);
            }
        }
        if (lane == 0) wcounts[wave] = min(wcnt, SEGCAP);
    }
    __syncthreads();                          // tile + queue + counts ready

    const int c0s = wcounts[0];
    const int c01 = c0s + wcounts[1];
    const int c012 = c01 + wcounts[2];
    const int total = c012 + wcounts[3];

    // one thread = one point; TWO independent insert chains (R18-proven)
    for (int slot = tid; slot < total; slot += KBLOCK) {
        int seg, idx;
        if (slot < c0s)      { seg = 0; idx = slot; }
        else if (slot < c01) { seg = 1; idx = slot - c0s; }
        else if (slot < c012){ seg = 2; idx = slot - c01; }
        else                 { seg = 3; idx = slot - c012; }
        unsigned pk = queue[seg * SEGCAP + idx];
        int i  = (int)(pk & 0x1FFFFu);
        int xl = (int)((pk >> 17) & 63u);
        int y  = (int)((pk >> 23) & 63u);
        float u = unproj_range[i];

        const double sent = __longlong_as_double((long long)SENTINEL_BITS);
        double a0 = sent, a1 = sent, a2 = sent, a3 = sent,
               a4 = sent, a5 = sent, a6 = sent;
        double b0 = sent, b1 = sent, b2 = sent, b3 = sent,
               b4 = sent, b5 = sent, b6 = sent;

        INSF_P(a, __longlong_as_double((long long)((1ull << 62) | 24ull))); // center

#pragma unroll
        for (int dy = -3; dy <= 3; ++dy) {
            int rb = (y + dy + 3) * TCOLS + xl + 3;
#pragma unroll
            for (int dx = -3; dx <= 3; ++dx) {
                const int j = (dy + 3) * 7 + (dx + 3);
                if (j == 24) continue;        // center handled above
                if (j & 1) { CANDP(a, j, rb, dx); }
                else       { CANDP(b, j, rb, dx); }
            }
        }

        // register half-cleaner: the 7 smallest of the 14 (set, order-free)
        double m0 = fmin(a0, b6);
        double m1 = fmin(a1, b5);
        double m2 = fmin(a2, b4);
        double m3 = fmin(a3, b3);
        double m4 = fmin(a4, b2);
        double m5 = fmin(a5, b1);
        double m6 = fmin(a6, b0);

        const double cutmax = __longlong_as_double((long long)CUTOFF_KEYMAX);
        int c0, c1, c2, c3, c4, c5, c6;
        // winner classes gathered from global proj_argmax (L2-hot; R13-proven)
#define CLSK(MK, CK) do {                                                \
        long long kb = __double_as_longlong(MK);                         \
        int j = (int)(kb & 63);                                          \
        bool sel = (MK) <= cutmax;                                       \
        int dy7 = (j * 37) >> 8;                                         \
        int sr = y + dy7 - 3;                                            \
        bool vrow = (unsigned)sr < (unsigned)H;                          \
        int src = min(max(sr, 0), H - 1);                                \
        int colw = (tbase - 3 + xl + (j - dy7 * 7)) & (W - 1);           \
        int cc = proj_argmax[src * W + colw];                            \
        CK = (sel && vrow) ? cc : 0;                                     \
    } while (0)
        CLSK(m0, c0); CLSK(m1, c1); CLSK(m2, c2); CLSK(m3, c3);
        CLSK(m4, c4); CLSK(m5, c5); CLSK(m6, c6);
#undef CLSK

        int n0 = 1, n1 = 1, n2 = 1, n3 = 1, n4 = 1, n5 = 1, n6 = 1;
#define PAIRV(A, B) do { bool e = (c##A == c##B); n##A += e ? 1 : 0; n##B += e ? 1 : 0; } while (0)
        PAIRV(0,1); PAIRV(0,2); PAIRV(0,3); PAIRV(0,4); PAIRV(0,5); PAIRV(0,6);
        PAIRV(1,2); PAIRV(1,3); PAIRV(1,4); PAIRV(1,5); PAIRV(1,6);
        PAIRV(2,3); PAIRV(2,4); PAIRV(2,5); PAIRV(2,6);
        PAIRV(3,4); PAIRV(3,5); PAIRV(3,6);
        PAIRV(4,5); PAIRV(4,6);
        PAIRV(5,6);
#undef PAIRV

        int best = 0;
#define SCORE(K) do {                                                    \
        bool valid = (unsigned)(c##K - 1) < (unsigned)(NCLASSES - 1);    \
        int sc = valid ? ((n##K << 5) | (31 - c##K)) : 0;                \
        best = max(best, sc);                                            \
    } while (0)
        SCORE(0); SCORE(1); SCORE(2); SCORE(3); SCORE(4); SCORE(5); SCORE(6);
#undef SCORE
        int res = (best == 0) ? 1 : (31 - (best & 31));
        __builtin_nontemporal_store(res, &outv[i]);
    }
}

extern "C" void kernel_launch(void* const* d_in, const int* in_sizes, int n_in,
                              void* d_out, int out_size, void* d_ws, size_t ws_size,
                              hipStream_t stream) {
    const float* proj_range   = (const float*)d_in[0];
    const float* unproj_range = (const float*)d_in[1];
    const int*   proj_argmax  = (const int*)d_in[2];
    const int*   px           = (const int*)d_in[3];
    const int*   py           = (const int*)d_in[4];
    int* out = (int*)d_out;

    // Emulate numpy float32 pipeline for the inverse-gaussian table.
    InvG invg;
    float g[S2];
    for (int yy = 0; yy < SEARCH; ++yy) {
        for (int xx = 0; xx < SEARCH; ++xx) {
            float fdx = (float)xx - 3.0f;
            float fdy = (float)yy - 3.0f;
            float s   = fdx * fdx + fdy * fdy;
            float arg = -s / 2.0f;
            float e   = (float)exp((double)arg);
            float gg  = e / 6.2831855f;
            g[yy * SEARCH + xx] = gg;
        }
    }
    float r[8];
    for (int tt = 0; tt < 8; ++tt) r[tt] = g[tt];
    int ii;
    for (ii = 8; ii + 8 <= 48; ii += 8)
        for (int tt = 0; tt < 8; ++tt) r[tt] += g[ii + tt];
    float ssum = ((r[0] + r[1]) + (r[2] + r[3])) + ((r[4] + r[5]) + (r[6] + r[7]));
    for (; ii < S2; ++ii) ssum += g[ii];
    for (int tt = 0; tt < S2; ++tt) invg.v[tt] = 1.0f - (g[tt] / ssum);

    knn_kernel<<<NTILES * SPT, KBLOCK, 0, stream>>>(
        proj_range, unproj_range, proj_argmax, px, py, out, invg);
}